// Round 3
// baseline (1101.272 us; speedup 1.0000x reference)
//
#include <hip/hip_runtime.h>
#include <stdint.h>

#define TT 512
#define HB 256   // hidden
#define DD 128   // input dim

typedef _Float16 h2_t __attribute__((ext_vector_type(2)));
typedef _Float16 h8_t __attribute__((ext_vector_type(8)));
typedef float    f4_t __attribute__((ext_vector_type(4)));
typedef uint32_t u4_t __attribute__((ext_vector_type(4)));

// ws layout: ONLY the four fp16 (B*T,256) arrays, a = 0:gx_r 1:gx_mu 2:gx_h 3:beta.
// Total = 4 * 67108864 = 268435456 B = exactly 256 MiB. Nothing else in ws.
#define GX_SZ 67108864ull

// B^T tiles (4 x 64 KB, fp16 [c][k] XOR-swizzled) live in d_out (256 KB) as
// scratch; scan_k overwrites d_out with the final h afterwards.

__device__ __forceinline__ uint32_t pack_h2f(float lo, float hi) {
  h2_t h; h[0] = (_Float16)lo; h[1] = (_Float16)hi;
  return __builtin_bit_cast(uint32_t, h);
}

__device__ __forceinline__ float fdot2f(uint32_t a, uint32_t b, float c) {
  h2_t ha = __builtin_bit_cast(h2_t, a), hb = __builtin_bit_cast(h2_t, b);
#if __has_builtin(__builtin_amdgcn_fdot2)
  return __builtin_amdgcn_fdot2(ha, hb, c, false);
#else
  return c + (float)ha[0]*(float)hb[0] + (float)ha[1]*(float)hb[1];
#endif
}

// LDS-only barrier: do NOT drain vmcnt, so global prefetches stay in flight.
__device__ __forceinline__ void barrier_lds() {
  asm volatile("s_waitcnt lgkmcnt(0)" ::: "memory");
  __builtin_amdgcn_s_barrier();
  __builtin_amdgcn_sched_barrier(0);
}

// ---------------------------------------------------------------------------
// Kernel 1: build B^T tiles (fp16, [c][kpair] XOR-swizzled) into d_out scratch.
// 65536 threads; tile a: 256 c x 64 kpairs (K=128).
// ---------------------------------------------------------------------------
__global__ __launch_bounds__(256)
void pack_w(const float* __restrict__ Wr, const float* __restrict__ Wmu,
            const float* __restrict__ Wh, const float* __restrict__ Wtd,
            uint8_t* __restrict__ bt) {
  const int id = blockIdx.x * 256 + threadIdx.x;   // 0..65535
  const int a = id >> 14, rem = id & 16383;
  const int c = rem >> 6, kp = rem & 63;
  const float* W = (a==0) ? Wr : (a==1) ? Wmu : (a==2) ? Wh : Wtd;
  const int r0 = (a==3) ? 0 : 256;                 // Wx_g = W_g[H:], W_td full
  const uint32_t v = pack_h2f(W[(r0 + 2*kp)*256 + c], W[(r0 + 2*kp + 1)*256 + c]);
  *(uint32_t*)(bt + a*65536 + c*256 + ((kp*4) ^ ((c & 7) << 4))) = v;
}

// ---------------------------------------------------------------------------
// Kernel 2: pre-pass GEMM.  a=0..2: gx_g = x@Wx_g + b_g; a=3: beta.
// block: 256 thr, M-tile 128, N=256, K=128; f16 MFMA 16x16x32, fp32 accum.
// ---------------------------------------------------------------------------
__global__ __launch_bounds__(256, 2)
void gemm_pre(const float* __restrict__ x, const float* __restrict__ delta,
              const float* __restrict__ br, const float* __restrict__ bmu,
              const float* __restrict__ bh, const float* __restrict__ btd,
              const uint8_t* __restrict__ bt, uint8_t* __restrict__ ws) {
  __shared__ uint8_t BT[65536];
  const int a  = blockIdx.x & 3;
  const int m0 = (blockIdx.x >> 2) * 128;
  const int tid = threadIdx.x;
  const int l = tid & 63, w = tid >> 6;
  const float* Asrc = (a == 3) ? delta : x;
  const float* bias = (a==0) ? br : (a==1) ? bmu : (a==2) ? bh : btd;

  { // stage pre-swizzled B^T (64 KB, linear copy; L2-broadcast across blocks)
    const u4_t* s4 = (const u4_t*)(bt + (size_t)a*65536);
    u4_t* d4 = (u4_t*)BT;
    #pragma unroll
    for (int i = 0; i < 16; i++) d4[i*256 + tid] = s4[i*256 + tid];
  }
  __syncthreads();

  f4_t acc[2][16];
  #pragma unroll
  for (int rt = 0; rt < 2; rt++)
    #pragma unroll
    for (int nt = 0; nt < 16; nt++) acc[rt][nt] = (f4_t){0.f, 0.f, 0.f, 0.f};

  const int rbase = m0 + w*32 + (l & 15);
  #pragma unroll
  for (int ks = 0; ks < 4; ks++) {
    h8_t af[2];
    #pragma unroll
    for (int rt = 0; rt < 2; rt++) {            // A direct from global (coalesced)
      const float* ap = Asrc + (size_t)(rbase + rt*16)*128 + ks*32 + (l >> 4)*8;
      f4_t f0 = *(const f4_t*)ap;
      f4_t f1 = *(const f4_t*)(ap + 4);
      h8_t v;
      v[0]=(_Float16)f0[0]; v[1]=(_Float16)f0[1]; v[2]=(_Float16)f0[2]; v[3]=(_Float16)f0[3];
      v[4]=(_Float16)f1[0]; v[5]=(_Float16)f1[1]; v[6]=(_Float16)f1[2]; v[7]=(_Float16)f1[3];
      af[rt] = v;
    }
    #pragma unroll
    for (int nt = 0; nt < 16; nt++) {
      const int c = nt*16 + (l & 15);
      const int boff = c*256 + ((ks*64 + (l >> 4)*16) ^ ((c & 7) << 4));
      h8_t bf = __builtin_bit_cast(h8_t, *(const u4_t*)(BT + boff));
      acc[0][nt] = __builtin_amdgcn_mfma_f32_16x16x32_f16(af[0], bf, acc[0][nt], 0, 0, 0);
      acc[1][nt] = __builtin_amdgcn_mfma_f32_16x16x32_f16(af[1], bf, acc[1][nt], 0, 0, 0);
    }
  }

  _Float16* outp = (_Float16*)(ws + (size_t)a * GX_SZ);
  #pragma unroll
  for (int nt = 0; nt < 16; nt++) {
    const int c = nt*16 + (l & 15);
    const float bv = bias[c];
    #pragma unroll
    for (int rt = 0; rt < 2; rt++) {
      #pragma unroll
      for (int i = 0; i < 4; i++) {             // C layout: col=l&15, row=(l>>4)*4+i  [m89]
        const int row = m0 + w*32 + rt*16 + (l >> 4)*4 + i;
        float z = acc[rt][nt][i] + bv;
        if (a == 3) z = __expf(-fmaxf(z, 0.f)); // beta = exp(-relu(.))
        outp[(size_t)row*256 + c] = (_Float16)z;
      }
    }
  }
}

// ---------------------------------------------------------------------------
// Kernel 3: recurrent scan. 256 blocks (1 batch row/CU), 512 thr. Recurrent
// weights packed fp32->fp16-pairs into VGPRs from global at start; h exchanged
// via LDS; v_dot2_f32_f16 dots; K split 8-way/col + select-shfl reduce.
// 2 LDS-only barriers/step; gx/beta prefetched ahead.
// Pipeline invariant: top of iter t, bA = beta[t+1], bB = beta[t+2], so the
// in-loop load must fetch beta[t+3]  (round-2 bug: fetched t+2 -> off-by-one).
// ---------------------------------------------------------------------------
__global__ __launch_bounds__(512, 2)
void scan_k(const uint8_t* __restrict__ ws,
            const float* __restrict__ Wr, const float* __restrict__ Wmu,
            const float* __restrict__ Wh, float* __restrict__ out) {
  const int b = blockIdx.x;
  const int tid = threadIdx.x;
  const int l = tid & 63, w = tid >> 6, kq = l >> 3;

  __shared__ float hbf[256];   // hb = beta_t * h_{t-1}, fp32
  __shared__ float muv[256];   // mu gate
  __shared__ u4_t  hb4[40];    // hb fp16-pairs, [8 kq][5 u4] (pad breaks bank clash)
  __shared__ u4_t  rh4[40];    // r*hb fp16-pairs, same layout

  const int g   = w >> 2;                       // 0 = r-gate waves, 1 = mu-gate waves
  const int cP1 = (w & 3)*64 + (l & 7) + 8*kq;  // phase-1 finalize col (within gate)
  const int cD  = w*32 + (l & 7) + 8*(kq & 3);  // phase-2 finalize col (lanes<32)

  // ---- weights fp32 -> fp16-pair registers (one-time; W_*[:H] rows) ----
  const float* WG = (g == 0) ? Wr : Wmu;
  const int cb  = (w & 3)*64 + (l & 7);
  const int cb2 = w*32 + (l & 7);
  uint32_t w1[8][16];
  #pragma unroll
  for (int p = 0; p < 16; p++) {
    const int r = 2*(kq*16 + p);
    #pragma unroll
    for (int j = 0; j < 8; j++)
      w1[j][p] = pack_h2f(WG[r*256 + cb + 8*j], WG[(r+1)*256 + cb + 8*j]);
  }
  uint32_t w2[4][16];
  #pragma unroll
  for (int p = 0; p < 16; p++) {
    const int r = 2*(kq*16 + p);
    #pragma unroll
    for (int j = 0; j < 4; j++)
      w2[j][p] = pack_h2f(Wh[r*256 + cb2 + 8*j], Wh[(r+1)*256 + cb2 + 8*j]);
  }

  if (tid < 40)  hb4[tid] = (u4_t){0, 0, 0, 0};
  if (tid < 256) hbf[tid] = 0.f;

  // ---- per-thread global byte offsets into ws ----
  const uint32_t rowbase = (uint32_t)b * (TT*HB) * 2u;
  const uint32_t gxP1off = (uint32_t)g * (uint32_t)GX_SZ + rowbase + (uint32_t)cP1*2u;
  const uint32_t gxhoff  = 2u*(uint32_t)GX_SZ + rowbase + (uint32_t)cD*2u;
  const uint32_t betoff  = 3u*(uint32_t)GX_SZ + rowbase + (uint32_t)(cD & ~1)*2u;
  const bool fin2 = (l < 32);
  const bool evn2 = fin2 && ((l & 1) == 0);

  // prologue prefetch (t=0 gx; beta for t=1,2)
  uint16_t gxA  = *(const uint16_t*)(ws + gxP1off);
  uint16_t gxhA = fin2 ? *(const uint16_t*)(ws + gxhoff) : (uint16_t)0;
  uint32_t bA   = evn2 ? *(const uint32_t*)(ws + betoff + 1u*512u) : 0u;
  uint32_t bB   = evn2 ? *(const uint32_t*)(ws + betoff + 2u*512u) : 0u;

  __syncthreads();

  #pragma unroll 1
  for (int t = 0; t < TT; t++) {
    // prefetch next step (consumed next iteration; survives LDS-only barriers)
    const int tn  = (t < TT-1) ? t+1 : TT-1;
    const int tn3 = (t < TT-3) ? t+3 : TT-1;   // FIX: beta pipeline needs t+3
    uint16_t gxN  = *(const uint16_t*)(ws + gxP1off + (uint32_t)tn*512u);
    uint16_t gxhN = fin2 ? *(const uint16_t*)(ws + gxhoff + (uint32_t)tn*512u) : (uint16_t)0;
    uint32_t bC   = evn2 ? *(const uint32_t*)(ws + betoff + (uint32_t)tn3*512u) : 0u;

    // ================= Phase B: r & mu dots (K-slice kq, 8 cols/lane) ======
    float acc[8] = {0,0,0,0,0,0,0,0};
    #pragma unroll
    for (int q = 0; q < 4; q++) {
      u4_t hp = hb4[kq*5 + q];
      #pragma unroll
      for (int e = 0; e < 4; e++) {
        const uint32_t hv = hp[e];
        #pragma unroll
        for (int j = 0; j < 8; j++) acc[j] = fdot2f(w1[j][q*4 + e], hv, acc[j]);
      }
    }
    // select-reduce over kq bits; lane ends with full sum for col j==kq
    #pragma unroll
    for (int i = 0; i < 4; i++) {
      float snd = (l & 32) ? acc[i] : acc[i+4];
      float rcv = __shfl_xor(snd, 32, 64);
      acc[i] = ((l & 32) ? acc[i+4] : acc[i]) + rcv;
    }
    #pragma unroll
    for (int i = 0; i < 2; i++) {
      float snd = (l & 16) ? acc[i] : acc[i+2];
      float rcv = __shfl_xor(snd, 16, 64);
      acc[i] = ((l & 16) ? acc[i+2] : acc[i]) + rcv;
    }
    {
      float snd = (l & 8) ? acc[0] : acc[1];
      float rcv = __shfl_xor(snd, 8, 64);
      acc[0] = ((l & 8) ? acc[1] : acc[0]) + rcv;
    }
    {
      const float z = acc[0] + (float)__builtin_bit_cast(_Float16, gxA);
      const float v = 1.f / (1.f + __expf(-z));        // sigmoid
      const float vn = __shfl_down(v, 1, 64);
      if (g == 1) {
        muv[cP1] = v;
      } else if ((l & 1) == 0) {                       // pack rh = r * hb (pair)
        const float rh0 = v  * hbf[cP1];
        const float rh1 = vn * hbf[cP1 + 1];
        const int pp = cP1 >> 1;
        ((uint32_t*)rh4)[(pp >> 4)*20 + (pp & 15)] = pack_h2f(rh0, rh1);
      }
    }
    barrier_lds();

    // ================= Phase D: h_hat dots + state update ==================
    float a2[4] = {0,0,0,0};
    #pragma unroll
    for (int q = 0; q < 4; q++) {
      u4_t hp = rh4[kq*5 + q];
      #pragma unroll
      for (int e = 0; e < 4; e++) {
        const uint32_t hv = hp[e];
        #pragma unroll
        for (int j = 0; j < 4; j++) a2[j] = fdot2f(w2[j][q*4 + e], hv, a2[j]);
      }
    }
    #pragma unroll
    for (int i = 0; i < 4; i++) a2[i] += __shfl_xor(a2[i], 32, 64);
    #pragma unroll
    for (int i = 0; i < 2; i++) {
      float snd = (l & 16) ? a2[i] : a2[i+2];
      float rcv = __shfl_xor(snd, 16, 64);
      a2[i] = ((l & 16) ? a2[i+2] : a2[i]) + rcv;
    }
    {
      float snd = (l & 8) ? a2[0] : a2[1];
      float rcv = __shfl_xor(snd, 8, 64);
      a2[0] = ((l & 8) ? a2[1] : a2[0]) + rcv;
    }
    {
      const float z2 = a2[0] + (float)__builtin_bit_cast(_Float16, gxhA);
      const float e2 = __expf(2.f * z2);
      const float hh = 1.f - 2.f / (e2 + 1.f);         // tanh
      const float hbv = hbf[cD];
      const float hn  = hbv + muv[cD] * (hh - hbv);    // h = (1-mu)*hb + mu*hhat
      const float hn1 = __shfl_down(hn, 1, 64);
      if (evn2) {
        const h2_t bp = __builtin_bit_cast(h2_t, bA);  // beta_{t+1} pair
        const float hb0 = (float)bp[0] * hn;
        const float hb1 = (float)bp[1] * hn1;
        const int pp = cD >> 1;
        ((uint32_t*)hb4)[(pp >> 4)*20 + (pp & 15)] = pack_h2f(hb0, hb1);
        hbf[cD]     = hb0;
        hbf[cD + 1] = hb1;
        if (t == TT-1) {
          out[b*256 + cD]     = hn;
          out[b*256 + cD + 1] = hn1;
        }
      }
    }
    gxA = gxN; gxhA = gxhN; bA = bB; bB = bC;
    barrier_lds();
  }
}

// ---------------------------------------------------------------------------
extern "C" void kernel_launch(void* const* d_in, const int* in_sizes, int n_in,
                              void* d_out, int out_size, void* d_ws, size_t ws_size,
                              hipStream_t stream) {
  const float* x    = (const float*)d_in[0];
  const float* delta= (const float*)d_in[1];
  const float* Wmu  = (const float*)d_in[2];
  const float* bmu  = (const float*)d_in[3];
  const float* Wr   = (const float*)d_in[4];
  const float* br   = (const float*)d_in[5];
  const float* Wh   = (const float*)d_in[6];
  const float* bh   = (const float*)d_in[7];
  const float* Wtd  = (const float*)d_in[8];
  const float* btd  = (const float*)d_in[9];
  uint8_t* ws = (uint8_t*)d_ws;
  uint8_t* bt = (uint8_t*)d_out;                 // 256 KB scratch, overwritten by h
  float* out = (float*)d_out;

  hipLaunchKernelGGL(pack_w,   dim3(256),  dim3(256), 0, stream, Wr, Wmu, Wh, Wtd, bt);
  hipLaunchKernelGGL(gemm_pre, dim3(4096), dim3(256), 0, stream, x, delta, br, bmu, bh, btd, bt, ws);
  hipLaunchKernelGGL(scan_k,   dim3(256),  dim3(512), 0, stream, ws, Wr, Wmu, Wh, out);
}

// Round 8
// 1005.551 us; speedup vs baseline: 1.0952x; 1.0952x over previous
//
#include <hip/hip_runtime.h>
#include <stdint.h>

#define TT 512
#define HB 256   // hidden
#define DD 128   // input dim

typedef _Float16 h2_t __attribute__((ext_vector_type(2)));
typedef _Float16 h8_t __attribute__((ext_vector_type(8)));
typedef float    f4_t __attribute__((ext_vector_type(4)));
typedef uint32_t u4_t __attribute__((ext_vector_type(4)));

// ws layout: ONLY the four fp16 (B*T,256) arrays, a = 0:gx_r 1:gx_mu 2:gx_h 3:beta.
// Total = 4 * 67108864 = exactly 256 MiB.
#define GX_SZ 67108864ull

__device__ __forceinline__ uint32_t pack_h2f(float lo, float hi) {
  h2_t h; h[0] = (_Float16)lo; h[1] = (_Float16)hi;
  return __builtin_bit_cast(uint32_t, h);
}

// f16-pair dot with F32 ACCUMULATION (round-3-proven numerics).
// v_dot2_f32_f16: one instruction, D.f32 = a.lo*b.lo + a.hi*b.hi + c.
__device__ __forceinline__ float fdot2f(uint32_t a, uint32_t b, float c) {
#if __has_builtin(__builtin_amdgcn_fdot2)
  return __builtin_amdgcn_fdot2(__builtin_bit_cast(h2_t, a),
                                __builtin_bit_cast(h2_t, b), c, false);
#else
  asm("v_dot2_f32_f16 %0, %1, %2, %0" : "+v"(c) : "v"(a), "v"(b));
  return c;
#endif
}

// DPP cross-lane (VALU pipe, zero LDS traffic). 0xB1 = quad_perm(1,0,3,2) = xor1;
// 0x4E = quad_perm(2,3,0,1) = xor2. ds_swizzle 0x101F = xor4 (1 LDS-pipe op).
__device__ __forceinline__ float dpp_xor1(float x) {
  return __builtin_bit_cast(float, __builtin_amdgcn_update_dpp(
      0, __builtin_bit_cast(int, x), 0xB1, 0xF, 0xF, true));
}
__device__ __forceinline__ float dpp_xor2(float x) {
  return __builtin_bit_cast(float, __builtin_amdgcn_update_dpp(
      0, __builtin_bit_cast(int, x), 0x4E, 0xF, 0xF, true));
}
__device__ __forceinline__ float swz_xor4(float x) {
  return __builtin_bit_cast(float, __builtin_amdgcn_ds_swizzle(
      __builtin_bit_cast(int, x), 0x101F));
}

// LDS-only barrier: do NOT drain vmcnt, so global prefetches stay in flight.
__device__ __forceinline__ void barrier_lds() {
  asm volatile("s_waitcnt lgkmcnt(0)" ::: "memory");
  __builtin_amdgcn_s_barrier();
  __builtin_amdgcn_sched_barrier(0);
}

// ---------------------------------------------------------------------------
// Kernel 1: build B^T tiles (fp16, [c][kpair] XOR-swizzled) into d_out scratch.
// ---------------------------------------------------------------------------
__global__ __launch_bounds__(256)
void pack_w(const float* __restrict__ Wr, const float* __restrict__ Wmu,
            const float* __restrict__ Wh, const float* __restrict__ Wtd,
            uint8_t* __restrict__ bt) {
  const int id = blockIdx.x * 256 + threadIdx.x;   // 0..65535
  const int a = id >> 14, rem = id & 16383;
  const int c = rem >> 6, kp = rem & 63;
  const float* W = (a==0) ? Wr : (a==1) ? Wmu : (a==2) ? Wh : Wtd;
  const int r0 = (a==3) ? 0 : 256;                 // Wx_g = W_g[H:], W_td full
  const uint32_t v = pack_h2f(W[(r0 + 2*kp)*256 + c], W[(r0 + 2*kp + 1)*256 + c]);
  *(uint32_t*)(bt + a*65536 + c*256 + ((kp*4) ^ ((c & 7) << 4))) = v;
}

// ---------------------------------------------------------------------------
// Kernel 2: pre-pass GEMM (unchanged from round 3, which passed).
// ---------------------------------------------------------------------------
__global__ __launch_bounds__(256, 2)
void gemm_pre(const float* __restrict__ x, const float* __restrict__ delta,
              const float* __restrict__ br, const float* __restrict__ bmu,
              const float* __restrict__ bh, const float* __restrict__ btd,
              const uint8_t* __restrict__ bt, uint8_t* __restrict__ ws) {
  __shared__ uint8_t BT[65536];
  const int a  = blockIdx.x & 3;
  const int m0 = (blockIdx.x >> 2) * 128;
  const int tid = threadIdx.x;
  const int l = tid & 63, w = tid >> 6;
  const float* Asrc = (a == 3) ? delta : x;
  const float* bias = (a==0) ? br : (a==1) ? bmu : (a==2) ? bh : btd;

  {
    const u4_t* s4 = (const u4_t*)(bt + (size_t)a*65536);
    u4_t* d4 = (u4_t*)BT;
    #pragma unroll
    for (int i = 0; i < 16; i++) d4[i*256 + tid] = s4[i*256 + tid];
  }
  __syncthreads();

  f4_t acc[2][16];
  #pragma unroll
  for (int rt = 0; rt < 2; rt++)
    #pragma unroll
    for (int nt = 0; nt < 16; nt++) acc[rt][nt] = (f4_t){0.f, 0.f, 0.f, 0.f};

  const int rbase = m0 + w*32 + (l & 15);
  #pragma unroll
  for (int ks = 0; ks < 4; ks++) {
    h8_t af[2];
    #pragma unroll
    for (int rt = 0; rt < 2; rt++) {
      const float* ap = Asrc + (size_t)(rbase + rt*16)*128 + ks*32 + (l >> 4)*8;
      f4_t f0 = *(const f4_t*)ap;
      f4_t f1 = *(const f4_t*)(ap + 4);
      h8_t v;
      v[0]=(_Float16)f0[0]; v[1]=(_Float16)f0[1]; v[2]=(_Float16)f0[2]; v[3]=(_Float16)f0[3];
      v[4]=(_Float16)f1[0]; v[5]=(_Float16)f1[1]; v[6]=(_Float16)f1[2]; v[7]=(_Float16)f1[3];
      af[rt] = v;
    }
    #pragma unroll
    for (int nt = 0; nt < 16; nt++) {
      const int c = nt*16 + (l & 15);
      const int boff = c*256 + ((ks*64 + (l >> 4)*16) ^ ((c & 7) << 4));
      h8_t bf = __builtin_bit_cast(h8_t, *(const u4_t*)(BT + boff));
      acc[0][nt] = __builtin_amdgcn_mfma_f32_16x16x32_f16(af[0], bf, acc[0][nt], 0, 0, 0);
      acc[1][nt] = __builtin_amdgcn_mfma_f32_16x16x32_f16(af[1], bf, acc[1][nt], 0, 0, 0);
    }
  }

  _Float16* outp = (_Float16*)(ws + (size_t)a * GX_SZ);
  #pragma unroll
  for (int nt = 0; nt < 16; nt++) {
    const int c = nt*16 + (l & 15);
    const float bv = bias[c];
    #pragma unroll
    for (int rt = 0; rt < 2; rt++) {
      #pragma unroll
      for (int i = 0; i < 4; i++) {
        const int row = m0 + w*32 + rt*16 + (l >> 4)*4 + i;
        float z = acc[rt][nt][i] + bv;
        if (a == 3) z = __expf(-fmaxf(z, 0.f));
        outp[(size_t)row*256 + c] = (_Float16)z;
      }
    }
  }
}

// ---------------------------------------------------------------------------
// Kernel 3 (v4): recurrent scan. 256 blocks x 512 thr (1 row/CU, 8 waves).
// = round-3 numerics (v_dot2_f32_f16, f32 accum)  [known-passing]
// + v3 lane map: K-slice on LOW bits (kq=l&7), reduce via DPP xor1/xor2 +
//   one ds_swizzle xor4  [algebra identical to round-3's select-exchange]
// + waves_per_eu(2,2) so weights stay in arch VGPRs (no AGPR copies).
// ---------------------------------------------------------------------------
__global__ __launch_bounds__(512)
__attribute__((amdgpu_waves_per_eu(2, 2)))
void scan_k(const uint8_t* __restrict__ ws,
            const float* __restrict__ Wr, const float* __restrict__ Wmu,
            const float* __restrict__ Wh, float* __restrict__ out) {
  const int b = blockIdx.x;
  const int tid = threadIdx.x;
  const int l = tid & 63, w = tid >> 6;
  const int kq = l & 7, co = l >> 3;
  const int b0 = l & 1, b1 = (l >> 1) & 1, b2 = (l >> 2) & 1;

  __shared__ __align__(16) float hbf[256];  // hb = beta_t * h_{t-1}, fp32
  __shared__ float muv[256];                // mu gate
  __shared__ u4_t  hb4[40];                 // hb f16-pairs [8 kq][5 u4] (pad)
  __shared__ u4_t  rh4[40];                 // r*hb f16-pairs, same layout

  const int g = w >> 2;                     // 0 = r-gate waves, 1 = mu-gate
  const int c1 = (w & 3)*64 + l;            // phase-B col (within gate)
  const int cD = w*32 + co*4 + (l & 3);     // phase-D col (dup over l&4)

  // ---- weights fp32 -> f16-pair VGPRs (one-time) ----
  const float* WG = (g == 0) ? Wr : Wmu;
  uint32_t w1b[8][16];
  #pragma unroll
  for (int p = 0; p < 16; p++) {
    const int r0 = kq*32 + 2*p;
    #pragma unroll
    for (int j = 0; j < 8; j++) {
      const int c = (w & 3)*64 + co*8 + j;
      w1b[j][p] = pack_h2f(WG[r0*256 + c], WG[(r0+1)*256 + c]);
    }
  }
  uint32_t w2b[4][16];
  #pragma unroll
  for (int p = 0; p < 16; p++) {
    const int r0 = kq*32 + 2*p;
    #pragma unroll
    for (int j = 0; j < 4; j++) {
      const int c = w*32 + co*4 + j;
      w2b[j][p] = pack_h2f(Wh[r0*256 + c], Wh[(r0+1)*256 + c]);
    }
  }

  if (tid < 40)  hb4[tid] = (u4_t){0, 0, 0, 0};
  if (tid < 256) hbf[tid] = 0.f;

  // ---- per-thread global byte offsets into ws ----
  const uint32_t rowbase = (uint32_t)b * (TT*HB) * 2u;
  const uint32_t gxP1off = (uint32_t)g * (uint32_t)GX_SZ + rowbase + (uint32_t)c1*2u;
  const uint32_t gxhoff  = 2u*(uint32_t)GX_SZ + rowbase + (uint32_t)cD*2u;
  const uint32_t betoff  = 3u*(uint32_t)GX_SZ + rowbase + (uint32_t)(cD & ~1)*2u;

  // prologue prefetch: gx[0], gxh[0], beta[1]
  uint16_t gxA  = *(const uint16_t*)(ws + gxP1off);
  uint16_t gxhA = *(const uint16_t*)(ws + gxhoff);
  uint32_t bA   = *(const uint32_t*)(ws + betoff + 1u*512u);

  __syncthreads();

  #pragma unroll 1
  for (int t = 0; t < TT; t++) {
    // prefetch for next iter (survives LDS-only barriers).
    // invariant: top of iter t, bA = beta[t+1]  ->  load beta[t+2] here.
    const int tn  = (t < TT-1) ? t+1 : TT-1;
    const int tn2 = (t < TT-2) ? t+2 : TT-1;
    uint16_t gxN  = *(const uint16_t*)(ws + gxP1off + (uint32_t)tn*512u);
    uint16_t gxhN = *(const uint16_t*)(ws + gxhoff + (uint32_t)tn*512u);
    uint32_t bN   = *(const uint32_t*)(ws + betoff + (uint32_t)tn2*512u);

    // ============ Phase B: r & mu dots (slice kq=l&7, 8 cols/lane) =========
    float a8[8] = {0,0,0,0,0,0,0,0};
    #pragma unroll
    for (int q = 0; q < 4; q++) {
      u4_t hp = hb4[kq*5 + q];
      #pragma unroll
      for (int e = 0; e < 4; e++) {
        const uint32_t hv = hp[e];
        #pragma unroll
        for (int j = 0; j < 8; j++) a8[j] = fdot2f(w1b[j][q*4 + e], hv, a8[j]);
      }
    }
    // select-exchange reduce over kq bits 0(DPP xor1),1(DPP xor2),2(swz xor4);
    // lane l ends owning col c1 = base + l.
    float s4[4];
    #pragma unroll
    for (int j = 0; j < 4; j++) {
      const float keep = b0 ? a8[2*j+1] : a8[2*j];
      const float snd  = b0 ? a8[2*j]   : a8[2*j+1];
      s4[j] = keep + dpp_xor1(snd);
    }
    float s2[2];
    #pragma unroll
    for (int j = 0; j < 2; j++) {
      const float keep = b1 ? s4[2*j+1] : s4[2*j];
      const float snd  = b1 ? s4[2*j]   : s4[2*j+1];
      s2[j] = keep + dpp_xor2(snd);
    }
    {
      const float keep = b2 ? s2[1] : s2[0];
      const float snd  = b2 ? s2[0] : s2[1];
      const float sum = keep + swz_xor4(snd);

      const float z = sum + (float)__builtin_bit_cast(_Float16, gxA);
      const float v = 1.f / (1.f + __expf(-z));        // sigmoid
      if (g == 1) {
        muv[c1] = v;
      } else {
        const float vn = dpp_xor1(v);                  // r at col c1^1
        const float2 hb2 = *(const float2*)&hbf[c1 & ~1];
        const float rh0 = v  * hb2.x;
        const float rh1 = vn * hb2.y;
        if (b0 == 0) {
          const int pp = c1 >> 1;
          ((uint32_t*)rh4)[(pp >> 4)*20 + (pp & 15)] = pack_h2f(rh0, rh1);
        }
      }
    }
    barrier_lds();

    // ============ Phase D: h_hat dots + state update =======================
    float d4v[4] = {0,0,0,0};
    #pragma unroll
    for (int q = 0; q < 4; q++) {
      u4_t hp = rh4[kq*5 + q];
      #pragma unroll
      for (int e = 0; e < 4; e++) {
        const uint32_t hv = hp[e];
        #pragma unroll
        for (int j = 0; j < 4; j++) d4v[j] = fdot2f(w2b[j][q*4 + e], hv, d4v[j]);
      }
    }
    float t2[2];
    #pragma unroll
    for (int j = 0; j < 2; j++) {
      const float keep = b0 ? d4v[2*j+1] : d4v[2*j];
      const float snd  = b0 ? d4v[2*j]   : d4v[2*j+1];
      t2[j] = keep + dpp_xor1(snd);
    }
    float t1;
    {
      const float keep = b1 ? t2[1] : t2[0];
      const float snd  = b1 ? t2[0] : t2[1];
      t1 = keep + dpp_xor2(snd);
    }
    const float sum2 = t1 + swz_xor4(t1);              // butterfly over kq bit2

    {
      const float z2 = sum2 + (float)__builtin_bit_cast(_Float16, gxhA);
      const float e2 = __expf(2.f * z2);
      const float hh = 1.f - 2.f / (e2 + 1.f);         // tanh
      const float hbv = hbf[cD];
      const float hn  = hbv + muv[cD] * (hh - hbv);    // (1-mu)*hb + mu*hhat
      const float vn  = dpp_xor1(hn);                  // h at col cD^1
      if ((l & 5) == 0) {                              // one writer per col-pair
        const h2_t bp = __builtin_bit_cast(h2_t, bA);  // beta[t+1] pair
        const float hb0 = (float)bp[0] * hn;
        const float hb1 = (float)bp[1] * vn;
        const int pp = cD >> 1;
        ((uint32_t*)hb4)[(pp >> 4)*20 + (pp & 15)] = pack_h2f(hb0, hb1);
        *(float2*)&hbf[cD] = (float2){hb0, hb1};
        if (t == TT-1) *(float2*)(out + b*256 + cD) = (float2){hn, vn};
      }
    }
    gxA = gxN; gxhA = gxhN; bA = bN;
    barrier_lds();
  }
}

// ---------------------------------------------------------------------------
extern "C" void kernel_launch(void* const* d_in, const int* in_sizes, int n_in,
                              void* d_out, int out_size, void* d_ws, size_t ws_size,
                              hipStream_t stream) {
  const float* x    = (const float*)d_in[0];
  const float* delta= (const float*)d_in[1];
  const float* Wmu  = (const float*)d_in[2];
  const float* bmu  = (const float*)d_in[3];
  const float* Wr   = (const float*)d_in[4];
  const float* br   = (const float*)d_in[5];
  const float* Wh   = (const float*)d_in[6];
  const float* bh   = (const float*)d_in[7];
  const float* Wtd  = (const float*)d_in[8];
  const float* btd  = (const float*)d_in[9];
  uint8_t* ws = (uint8_t*)d_ws;
  uint8_t* bt = (uint8_t*)d_out;                 // 256 KB scratch, overwritten by h
  float* out = (float*)d_out;

  hipLaunchKernelGGL(pack_w,   dim3(256),  dim3(256), 0, stream, Wr, Wmu, Wh, Wtd, bt);
  hipLaunchKernelGGL(gemm_pre, dim3(4096), dim3(256), 0, stream, x, delta, br, bmu, bh, btd, bt, ws);
  hipLaunchKernelGGL(scan_k,   dim3(256),  dim3(512), 0, stream, ws, Wr, Wmu, Wh, out);
}